// Round 13
// baseline (171.262 us; speedup 1.0000x reference)
//
#include <hip/hip_runtime.h>
#include <hip/hip_bf16.h>
#include <hip/hip_fp16.h>

// CausalSelfAttention  B=4, S=2048, D=1024 (single wide head), fp32 in/out.
// R13 = R12 + single change: PV un-paired -> 512 independent tiles
// (grid 8x16x4), longest-K-first (tm = 15-by), 64KB LDS OCC=2 gives true
// 2-blocks/CU co-residency (R12's paired 256 blocks were 1/CU: barrier
// drains un-hidden -> ~17% util; scores' 544 blocks at 2/CU hit ~33%).

using bf16 = __hip_bfloat16;
typedef __bf16 bf16x8 __attribute__((ext_vector_type(8)));
typedef float f32x4 __attribute__((ext_vector_type(4)));

__device__ __forceinline__ void load_lds_16B(const void* g, void* l) {
  __builtin_amdgcn_global_load_lds(
      (const __attribute__((address_space(1))) unsigned int*)g,
      (__attribute__((address_space(3))) unsigned int*)l, 16, 0, 0);
}

template <int N>
__device__ __forceinline__ void waitcnt_vm() {
  if constexpr (N == 10) asm volatile("s_waitcnt vmcnt(10)" ::: "memory");
  else if constexpr (N == 8) asm volatile("s_waitcnt vmcnt(8)" ::: "memory");
  else if constexpr (N == 6) asm volatile("s_waitcnt vmcnt(6)" ::: "memory");
  else if constexpr (N == 5) asm volatile("s_waitcnt vmcnt(5)" ::: "memory");
  else asm volatile("s_waitcnt vmcnt(0)" ::: "memory");
}

// XOR bits[6:4] by bits[9:7] (involution). 0 bank conflicts (R2-R12 rocprof).
__device__ __forceinline__ int swz(int o) { return o ^ (((o >> 7) & 7) << 4); }

// ---------------------------------------------------------------------------
// NT GEMM: C[M,N] = A[M,K]*B[N,K]^T, strides lda/ldb/ldc (elements).
// WM x WN waves, wave tile (BM/WM) x (BN/WN). BK=64 as two kc=32 chunks.
// 8 phases / 2 K-tiles; staging on threads < STHR; counted vmcnt at P4/P8.
// OUT: 1 = bf16
//      3 = bf16 exp(S/32) causal-masked + shfl/atomic row-sums into aux
//      4 = fp32 / sums[row]  (aux = sums)
// KLIM: causal K-limit; NPASS==1 -> tm reversed (longest-K dispatched first);
// NPASS==2 -> block does row-tiles y and 2*gridDim.y-1-y.
// ---------------------------------------------------------------------------
template <int BM, int BN, int WM, int WN, int STHR, int OCC, int OUT,
          bool CSKIP, bool KLIM, int NPASS>
__global__ __launch_bounds__(WM* WN * 64, OCC) void gemmT(
    const bf16* __restrict__ A, const bf16* __restrict__ Bm, void* __restrict__ Cv,
    int K, int lda, int ldb, int ldc, long sAz, long sBz, long sCzBytes,
    void* __restrict__ aux) {
  constexpr int MR = BM / WM / 16, NR = BN / WN / 16, MH2 = MR / 2;
  constexpr int AKC = BM * 64;   // bytes per A kc-chunk [BM][32]bf16
  constexpr int BKC = BN * 64;   // bytes per B kc-chunk
  constexpr int DBSTR = 2 * (AKC + BKC);
  constexpr int CHUNK = STHR * 16;
  constexpr int ACALLS = AKC / CHUNK;
  constexpr int BCALLS = BKC / CHUNK;
  constexpr int VM_LEAVE = ACALLS + 2 * BCALLS;

  const int tn = blockIdx.x, z = blockIdx.z;
  if (CSKIP && (long)tn * BN >= (long)blockIdx.y * BM + BM) return;
  A += (long)z * sAz;
  Bm += (long)z * sBz;
  char* C = (char*)Cv + (long)z * sCzBytes;

  __shared__ __align__(128) char sm[2 * DBSTR];
  const int tid = threadIdx.x, lane = tid & 63, wv = tid >> 6;
  const int wr = wv / WN, wc = wv % WN;
  const int ldsw = wv * 1024;
  const int ts = (tid < STHR) ? tid : 0;

  int aoff[MR], boff[NR];
#pragma unroll
  for (int m = 0; m < MR; m++)
    aoff[m] = swz((wr * (BM / WM) + m * 16 + (lane & 15)) * 64 + (lane >> 4) * 16);
#pragma unroll
  for (int n = 0; n < NR; n++)
    boff[n] = 2 * AKC + swz((wc * (BN / WN) + n * 16 + (lane & 15)) * 64 + (lane >> 4) * 16);

  const char* srcB[BCALLS];
#pragma unroll
  for (int c = 0; c < BCALLS; c++) {
    int os = swz(c * CHUNK + ts * 16);
    srcB[c] = (const char*)(Bm + ((long)tn * BN + (os >> 6)) * ldb) + (os & 63);
  }

  for (int pass = 0; pass < NPASS; ++pass) {
    const int tm = (NPASS == 2)
                       ? (pass == 0 ? blockIdx.y : 2 * (int)gridDim.y - 1 - (int)blockIdx.y)
                       : (KLIM ? ((int)gridDim.y - 1 - (int)blockIdx.y)  // longest-first
                               : (int)blockIdx.y);

    int kEnd = K;
    if (KLIM) kEnd = min(tm * BM + BM, K);  // causal PV: E[q,k]==0 for k>q
    int nt = kEnd >> 6;
    if (KLIM) nt = (nt + 1) & ~1;
    const int NI = nt >> 1;

    const char* srcA[ACALLS];
#pragma unroll
    for (int c = 0; c < ACALLS; c++) {
      int os = swz(c * CHUNK + ts * 16);
      srcA[c] = (const char*)(A + ((long)tm * BM + (os >> 6)) * lda) + (os & 63);
    }
    auto stageA = [&](int t, int kc) {
      if (tid < STHR) {
#pragma unroll
        for (int c = 0; c < ACALLS; c++)
          load_lds_16B(srcA[c] + (long)t * 128 + kc * 64,
                       sm + (t & 1) * DBSTR + kc * AKC + c * CHUNK + ldsw);
      }
    };
    auto stageB = [&](int t, int kc) {
      if (tid < STHR) {
#pragma unroll
        for (int c = 0; c < BCALLS; c++)
          load_lds_16B(srcB[c] + (long)t * 128 + kc * 64,
                       sm + (t & 1) * DBSTR + 2 * AKC + kc * BKC + c * CHUNK + ldsw);
      }
    };

    f32x4 acc[MR][NR] = {};
    bf16x8 bfr[2][NR];
    bf16x8 afrA[MH2], afrB[MH2];

#define LDB(DBUF, KC)                                                          \
  _Pragma("unroll") for (int n = 0; n < NR; n++)                               \
      bfr[KC][n] = *(const bf16x8*)(sm + (DBUF)*DBSTR + (KC)*BKC + boff[n]);
#define LDA(DBUF, KC, MH, DST)                                                 \
  _Pragma("unroll") for (int m = 0; m < MH2; m++)                              \
      DST[m] = *(const bf16x8*)(sm + (DBUF)*DBSTR + (KC)*AKC + aoff[(MH)*MH2 + m]);
#define MFMAS(KC, MH, AFR)                                                     \
  __builtin_amdgcn_s_setprio(1);                                               \
  _Pragma("unroll") for (int m = 0; m < MH2; m++)                              \
      _Pragma("unroll") for (int n = 0; n < NR; n++)                           \
          acc[(MH)*MH2 + m][n] = __builtin_amdgcn_mfma_f32_16x16x32_bf16(      \
              AFR[m], bfr[KC][n], acc[(MH)*MH2 + m][n], 0, 0, 0);              \
  __builtin_amdgcn_s_setprio(0);
#define BAR1()                                                                 \
  __builtin_amdgcn_s_barrier();                                                \
  asm volatile("s_waitcnt lgkmcnt(0)" ::: "memory");                           \
  __builtin_amdgcn_sched_barrier(0);
#define BAR2() __builtin_amdgcn_s_barrier();

    // prologue: tile0 fully + tile1 minus Ak1 (completed by first P1)
    stageB(0, 0); stageA(0, 0); stageB(0, 1); stageA(0, 1);
    stageB(1, 0); stageA(1, 0); stageB(1, 1);
    waitcnt_vm<VM_LEAVE>();
    __builtin_amdgcn_s_barrier();

    for (int i = 0; i < NI - 1; i++) {
      const int ta = 2 * i, tb = 2 * i + 1;
      LDB(0, 0); LDA(0, 0, 0, afrA); stageA(tb, 1);     BAR1(); MFMAS(0, 0, afrA); BAR2();
      LDA(0, 0, 1, afrB);            stageB(ta + 2, 0); BAR1(); MFMAS(0, 1, afrB); BAR2();
      LDB(0, 1); LDA(0, 1, 0, afrA); stageA(ta + 2, 0); BAR1(); MFMAS(1, 0, afrA); BAR2();
      LDA(0, 1, 1, afrB);            stageB(ta + 2, 1);
      waitcnt_vm<VM_LEAVE>();                           BAR1(); MFMAS(1, 1, afrB); BAR2();
      LDB(1, 0); LDA(1, 0, 0, afrA); stageA(ta + 2, 1); BAR1(); MFMAS(0, 0, afrA); BAR2();
      LDA(1, 0, 1, afrB);            stageB(tb + 2, 0); BAR1(); MFMAS(0, 1, afrB); BAR2();
      LDB(1, 1); LDA(1, 1, 0, afrA); stageA(tb + 2, 0); BAR1(); MFMAS(1, 0, afrA); BAR2();
      LDA(1, 1, 1, afrB);            stageB(tb + 2, 1);
      waitcnt_vm<VM_LEAVE>();                           BAR1(); MFMAS(1, 1, afrB); BAR2();
    }
    {  // tail: tiles nt-2, nt-1; no further staging
      const int tb = nt - 1;
      LDB(0, 0); LDA(0, 0, 0, afrA); stageA(tb, 1); BAR1(); MFMAS(0, 0, afrA); BAR2();
      LDA(0, 0, 1, afrB);                           BAR1(); MFMAS(0, 1, afrB); BAR2();
      LDB(0, 1); LDA(0, 1, 0, afrA);                BAR1(); MFMAS(1, 0, afrA); BAR2();
      LDA(0, 1, 1, afrB); waitcnt_vm<0>();          BAR1(); MFMAS(1, 1, afrB); BAR2();
      LDB(1, 0); LDA(1, 0, 0, afrA);                BAR1(); MFMAS(0, 0, afrA); BAR2();
      LDA(1, 0, 1, afrB);                           BAR1(); MFMAS(0, 1, afrB); BAR2();
      LDB(1, 1); LDA(1, 1, 0, afrA);                BAR1(); MFMAS(1, 0, afrA); BAR2();
      LDA(1, 1, 1, afrB);                           BAR1(); MFMAS(1, 1, afrB); BAR2();
    }
#undef LDB
#undef LDA
#undef MFMAS
#undef BAR1
#undef BAR2

    // epilogue: D row = (lane>>4)*4 + j, col = lane&15 (m89-verified)
    const int cr0 = tm * BM + wr * (BM / WM) + (lane >> 4) * 4;
    const int cc0 = tn * BN + wc * (BN / WN) + (lane & 15);

    if (OUT == 3) {
      // E = exp(S/32) bf16, causal mask; shfl row-sum + one atomic per row
      // per wave-column.
      float* sums = (float*)aux + (long)z * 2048;
#pragma unroll
      for (int m = 0; m < MR; m++) {
        float rs[4] = {0.f, 0.f, 0.f, 0.f};
#pragma unroll
        for (int n = 0; n < NR; n++)
#pragma unroll
          for (int j = 0; j < 4; j++) {
            long row = cr0 + m * 16 + j;
            long col = cc0 + n * 16;
            float e = (col <= row) ? __expf(acc[m][n][j] * 0.03125f) : 0.f;
            ((bf16*)C)[row * (long)ldc + col] = __float2bfloat16(e);
            rs[j] += e;
          }
#pragma unroll
        for (int o = 1; o < 16; o <<= 1) {
#pragma unroll
          for (int j = 0; j < 4; j++) rs[j] += __shfl_xor(rs[j], o);
        }
        if ((lane & 15) == 0) {
#pragma unroll
          for (int j = 0; j < 4; j++)
            atomicAdd(&sums[cr0 + m * 16 + j], rs[j]);
        }
      }
    } else {
#pragma unroll
      for (int m = 0; m < MR; m++) {
        float inv[4];
        if (OUT == 4) {
          const float* sums = (const float*)aux + (long)z * 2048;
#pragma unroll
          for (int j = 0; j < 4; j++) inv[j] = 1.0f / sums[cr0 + m * 16 + j];
        }
#pragma unroll
        for (int n = 0; n < NR; n++)
#pragma unroll
          for (int j = 0; j < 4; j++) {
            long row = cr0 + m * 16 + j;
            long col = cc0 + n * 16;
            if (OUT == 1)
              ((bf16*)C)[row * (long)ldc + col] = __float2bfloat16(acc[m][n][j]);
            else if (OUT == 4)
              ((float*)C)[row * (long)ldc + col] = acc[m][n][j] * inv[j];
            else
              ((float*)C)[row * (long)ldc + col] = acc[m][n][j];
          }
      }
    }
  }
}

// ---------------------------------------------------------------------------
// fused fp32 -> bf16 convert for x, Wq, Wk, Wv + zero-fill of sums (32KB).
// ---------------------------------------------------------------------------
__global__ __launch_bounds__(256) void cvt_all(const float* __restrict__ x,
                                               const float* __restrict__ wq,
                                               const float* __restrict__ wk,
                                               const float* __restrict__ wv,
                                               bf16* __restrict__ xb,
                                               bf16* __restrict__ wb,
                                               float* __restrict__ sums) {
  const int b = blockIdx.x;
  if (b >= 11264) {
    ((float4*)sums)[(b - 11264) * 256 + threadIdx.x] = float4{0.f, 0.f, 0.f, 0.f};
    return;
  }
  const float* src;
  bf16* dst;
  int i;
  if (b < 8192) { src = x; dst = xb; i = b * 256 + threadIdx.x; }
  else if (b < 9216) { src = wq; dst = wb; i = (b - 8192) * 256 + threadIdx.x; }
  else if (b < 10240) { src = wk; dst = wb + 1048576; i = (b - 9216) * 256 + threadIdx.x; }
  else { src = wv; dst = wb + 2097152; i = (b - 10240) * 256 + threadIdx.x; }
  float4 f = ((const float4*)src)[i];
  union { bf16 h[4]; uint2 u; } o;
  o.h[0] = __float2bfloat16(f.x);
  o.h[1] = __float2bfloat16(f.y);
  o.h[2] = __float2bfloat16(f.z);
  o.h[3] = __float2bfloat16(f.w);
  ((uint2*)dst)[i] = o.u;
}

// ---------------------------------------------------------------------------
// V (cols 2048.. of Cqkv, row stride 3072) -> Vt[b,d,s] (bf16), LDS 32x32
// ---------------------------------------------------------------------------
__global__ __launch_bounds__(256) void transposeV(const bf16* __restrict__ V,
                                                  bf16* __restrict__ Vt) {
  __shared__ bf16 t[32][33];
  const int b = blockIdx.z;
  const int s0 = blockIdx.x << 5;
  const int d0 = blockIdx.y << 5;
  const bf16* Vb = V + (long)b * 2048 * 3072;
  bf16* Vtb = Vt + (long)b * 1024 * 2048;
  const int lx = threadIdx.x & 31, ly = threadIdx.x >> 5;
#pragma unroll
  for (int r = 0; r < 32; r += 8)
    t[r + ly][lx] = Vb[(long)(s0 + r + ly) * 3072 + d0 + lx];
  __syncthreads();
#pragma unroll
  for (int r = 0; r < 32; r += 8)
    Vtb[(long)(d0 + r + ly) * 2048 + s0 + lx] = t[lx][r + ly];
}

// ---------------------------------------------------------------------------
// Workspace (160 MB):
//   [0,48M)    Cqkv bf16 [8192][3072]  (Q|K|V interleaved, ld=3072)
//   [48,64M)   Vt bf16 [4][1024][2048]
//   [64,96M)   E bf16 [4][2048][2048]  (exp(S/32), causal-masked)
//   [96M,+32K) sums fp32 [4][2048]     (atomic row-sums; zeroed by cvt_all)
//   [97,115M)  xb bf16 ; [115,121M) Wb bf16  (dead after QKV)
// ---------------------------------------------------------------------------
extern "C" void kernel_launch(void* const* d_in, const int* in_sizes, int n_in,
                              void* d_out, int out_size, void* d_ws, size_t ws_size,
                              hipStream_t stream) {
  const float* x = (const float*)d_in[0];
  const float* Wq = (const float*)d_in[1];
  const float* Wk = (const float*)d_in[2];
  const float* Wv = (const float*)d_in[3];

  const long MBy = 1 << 20;
  char* ws = (char*)d_ws;
  bf16* Cqkv = (bf16*)(ws);
  bf16* Vt = (bf16*)(ws + 48 * MBy);
  bf16* E = (bf16*)(ws + 64 * MBy);
  float* sums = (float*)(ws + 96 * MBy);
  bf16* xb = (bf16*)(ws + 97 * MBy);
  bf16* Wb = (bf16*)(ws + 115 * MBy);

  // 1) convert inputs to bf16 + zero sums (single dispatch)
  cvt_all<<<11272, 256, 0, stream>>>(x, Wq, Wk, Wv, xb, Wb, sums);

  // 2) fused QKV: [8192,3072] = xb * Wb^T. BM=256, BN=192, 8 waves (2x4,
  //    wave-tile 128x48), 112KB LDS, 512 blocks = 2 rounds. (61.8us, stable)
  gemmT<256, 192, 2, 4, 256, 2, 1, false, false, 1><<<dim3(16, 32), 512, 0, stream>>>(
      xb, Wb, Cqkv, 1024, 1024, 1024, 3072, 0L, 0L, 0L, nullptr);

  // 3) V transpose (V = Cqkv cols [2048,3072), row stride 3072)
  transposeV<<<dim3(64, 32, 4), 256, 0, stream>>>(Cqkv + 2048, Vt);

  // 4) scores+exp+rowsum: E = exp(Q*K^T/32) bf16 causal-masked; row-sums
  //    reduced in-epilogue and atomicAdd'ed into sums. 544 live blocks.
  gemmT<128, 128, 2, 2, 256, 2, 3, true, false, 1><<<dim3(16, 16, 4), 256, 0, stream>>>(
      Cqkv, Cqkv + 1024, E, 1024, 3072, 3072, 2048,
      2048L * 3072, 2048L * 3072, 2048L * 2048 * 2, sums);

  // 5) out = (E * Vt^T) / sums[row], fp32. R13: 512 UNPAIRED tiles
  //    (grid 8x16x4), longest-K-first (tm = 15-by), 64KB LDS OCC=2 ->
  //    2 blocks/CU co-residency hides barrier drains.
  gemmT<128, 128, 2, 2, 256, 2, 4, false, true, 1><<<dim3(8, 16, 4), 256, 0, stream>>>(
      E, Vt, d_out, 2048, 2048, 2048, 1024,
      2048L * 2048, 1024L * 2048, 2048L * 1024 * 4, sums);
}

// Round 14
// 161.157 us; speedup vs baseline: 1.0627x; 1.0627x over previous
//
#include <hip/hip_runtime.h>
#include <hip/hip_bf16.h>
#include <hip/hip_fp16.h>

// CausalSelfAttention  B=4, S=2048, D=1024 (single wide head), fp32 in/out.
// R14 = exact revert to R12 (best verified: 161.4us).
//   - QKV: 256x192, 8 waves (2x4), 112KB LDS, 512 blocks = 2 exact rounds.
//   - scores: 128^2, 4 waves, OCC2, CSKIP; epilogue writes E=exp(S/32) bf16
//     causal-masked and atomicAdd's row-sums (softmax pass eliminated).
//   - PV: 128^2, paired row-tiles (y, 15-y) = constant 2176 k-tile work per
//     block (R13 showed unpaired co-residency loses to enforced balance);
//     epilogue divides by sums[row].
//   - cvt_all converts inputs + zeroes sums every call (ws not re-poisoned).

using bf16 = __hip_bfloat16;
typedef __bf16 bf16x8 __attribute__((ext_vector_type(8)));
typedef float f32x4 __attribute__((ext_vector_type(4)));

__device__ __forceinline__ void load_lds_16B(const void* g, void* l) {
  __builtin_amdgcn_global_load_lds(
      (const __attribute__((address_space(1))) unsigned int*)g,
      (__attribute__((address_space(3))) unsigned int*)l, 16, 0, 0);
}

template <int N>
__device__ __forceinline__ void waitcnt_vm() {
  if constexpr (N == 10) asm volatile("s_waitcnt vmcnt(10)" ::: "memory");
  else if constexpr (N == 8) asm volatile("s_waitcnt vmcnt(8)" ::: "memory");
  else if constexpr (N == 6) asm volatile("s_waitcnt vmcnt(6)" ::: "memory");
  else if constexpr (N == 5) asm volatile("s_waitcnt vmcnt(5)" ::: "memory");
  else asm volatile("s_waitcnt vmcnt(0)" ::: "memory");
}

// XOR bits[6:4] by bits[9:7] (involution). 0 bank conflicts (R2-R13 rocprof).
__device__ __forceinline__ int swz(int o) { return o ^ (((o >> 7) & 7) << 4); }

// ---------------------------------------------------------------------------
// NT GEMM: C[M,N] = A[M,K]*B[N,K]^T, strides lda/ldb/ldc (elements).
// WM x WN waves, wave tile (BM/WM) x (BN/WN). BK=64 as two kc=32 chunks.
// 8 phases / 2 K-tiles; staging on threads < STHR; counted vmcnt at P4/P8.
// OUT: 1 = bf16
//      3 = bf16 exp(S/32) causal-masked + shfl/atomic row-sums into aux
//      4 = fp32 / sums[row]  (aux = sums)
// NPASS=2: block does row-tiles y and 2*gridDim.y-1-y (balanced causal K).
// ---------------------------------------------------------------------------
template <int BM, int BN, int WM, int WN, int STHR, int OCC, int OUT,
          bool CSKIP, bool KLIM, int NPASS>
__global__ __launch_bounds__(WM* WN * 64, OCC) void gemmT(
    const bf16* __restrict__ A, const bf16* __restrict__ Bm, void* __restrict__ Cv,
    int K, int lda, int ldb, int ldc, long sAz, long sBz, long sCzBytes,
    void* __restrict__ aux) {
  constexpr int MR = BM / WM / 16, NR = BN / WN / 16, MH2 = MR / 2;
  constexpr int AKC = BM * 64;   // bytes per A kc-chunk [BM][32]bf16
  constexpr int BKC = BN * 64;   // bytes per B kc-chunk
  constexpr int DBSTR = 2 * (AKC + BKC);
  constexpr int CHUNK = STHR * 16;
  constexpr int ACALLS = AKC / CHUNK;
  constexpr int BCALLS = BKC / CHUNK;
  constexpr int VM_LEAVE = ACALLS + 2 * BCALLS;

  const int tn = blockIdx.x, z = blockIdx.z;
  if (CSKIP && (long)tn * BN >= (long)blockIdx.y * BM + BM) return;
  A += (long)z * sAz;
  Bm += (long)z * sBz;
  char* C = (char*)Cv + (long)z * sCzBytes;

  __shared__ __align__(128) char sm[2 * DBSTR];
  const int tid = threadIdx.x, lane = tid & 63, wv = tid >> 6;
  const int wr = wv / WN, wc = wv % WN;
  const int ldsw = wv * 1024;
  const int ts = (tid < STHR) ? tid : 0;

  int aoff[MR], boff[NR];
#pragma unroll
  for (int m = 0; m < MR; m++)
    aoff[m] = swz((wr * (BM / WM) + m * 16 + (lane & 15)) * 64 + (lane >> 4) * 16);
#pragma unroll
  for (int n = 0; n < NR; n++)
    boff[n] = 2 * AKC + swz((wc * (BN / WN) + n * 16 + (lane & 15)) * 64 + (lane >> 4) * 16);

  const char* srcB[BCALLS];
#pragma unroll
  for (int c = 0; c < BCALLS; c++) {
    int os = swz(c * CHUNK + ts * 16);
    srcB[c] = (const char*)(Bm + ((long)tn * BN + (os >> 6)) * ldb) + (os & 63);
  }

  for (int pass = 0; pass < NPASS; ++pass) {
    const int tm = (NPASS == 2)
                       ? (pass == 0 ? blockIdx.y : 2 * (int)gridDim.y - 1 - (int)blockIdx.y)
                       : (int)blockIdx.y;

    int kEnd = K;
    if (KLIM) kEnd = min(tm * BM + BM, K);  // causal PV: E[q,k]==0 for k>q
    int nt = kEnd >> 6;
    if (KLIM) nt = (nt + 1) & ~1;
    const int NI = nt >> 1;

    const char* srcA[ACALLS];
#pragma unroll
    for (int c = 0; c < ACALLS; c++) {
      int os = swz(c * CHUNK + ts * 16);
      srcA[c] = (const char*)(A + ((long)tm * BM + (os >> 6)) * lda) + (os & 63);
    }
    auto stageA = [&](int t, int kc) {
      if (tid < STHR) {
#pragma unroll
        for (int c = 0; c < ACALLS; c++)
          load_lds_16B(srcA[c] + (long)t * 128 + kc * 64,
                       sm + (t & 1) * DBSTR + kc * AKC + c * CHUNK + ldsw);
      }
    };
    auto stageB = [&](int t, int kc) {
      if (tid < STHR) {
#pragma unroll
        for (int c = 0; c < BCALLS; c++)
          load_lds_16B(srcB[c] + (long)t * 128 + kc * 64,
                       sm + (t & 1) * DBSTR + 2 * AKC + kc * BKC + c * CHUNK + ldsw);
      }
    };

    f32x4 acc[MR][NR] = {};
    bf16x8 bfr[2][NR];
    bf16x8 afrA[MH2], afrB[MH2];

#define LDB(DBUF, KC)                                                          \
  _Pragma("unroll") for (int n = 0; n < NR; n++)                               \
      bfr[KC][n] = *(const bf16x8*)(sm + (DBUF)*DBSTR + (KC)*BKC + boff[n]);
#define LDA(DBUF, KC, MH, DST)                                                 \
  _Pragma("unroll") for (int m = 0; m < MH2; m++)                              \
      DST[m] = *(const bf16x8*)(sm + (DBUF)*DBSTR + (KC)*AKC + aoff[(MH)*MH2 + m]);
#define MFMAS(KC, MH, AFR)                                                     \
  __builtin_amdgcn_s_setprio(1);                                               \
  _Pragma("unroll") for (int m = 0; m < MH2; m++)                              \
      _Pragma("unroll") for (int n = 0; n < NR; n++)                           \
          acc[(MH)*MH2 + m][n] = __builtin_amdgcn_mfma_f32_16x16x32_bf16(      \
              AFR[m], bfr[KC][n], acc[(MH)*MH2 + m][n], 0, 0, 0);              \
  __builtin_amdgcn_s_setprio(0);
#define BAR1()                                                                 \
  __builtin_amdgcn_s_barrier();                                                \
  asm volatile("s_waitcnt lgkmcnt(0)" ::: "memory");                           \
  __builtin_amdgcn_sched_barrier(0);
#define BAR2() __builtin_amdgcn_s_barrier();

    // prologue: tile0 fully + tile1 minus Ak1 (completed by first P1)
    stageB(0, 0); stageA(0, 0); stageB(0, 1); stageA(0, 1);
    stageB(1, 0); stageA(1, 0); stageB(1, 1);
    waitcnt_vm<VM_LEAVE>();
    __builtin_amdgcn_s_barrier();

    for (int i = 0; i < NI - 1; i++) {
      const int ta = 2 * i, tb = 2 * i + 1;
      LDB(0, 0); LDA(0, 0, 0, afrA); stageA(tb, 1);     BAR1(); MFMAS(0, 0, afrA); BAR2();
      LDA(0, 0, 1, afrB);            stageB(ta + 2, 0); BAR1(); MFMAS(0, 1, afrB); BAR2();
      LDB(0, 1); LDA(0, 1, 0, afrA); stageA(ta + 2, 0); BAR1(); MFMAS(1, 0, afrA); BAR2();
      LDA(0, 1, 1, afrB);            stageB(ta + 2, 1);
      waitcnt_vm<VM_LEAVE>();                           BAR1(); MFMAS(1, 1, afrB); BAR2();
      LDB(1, 0); LDA(1, 0, 0, afrA); stageA(ta + 2, 1); BAR1(); MFMAS(0, 0, afrA); BAR2();
      LDA(1, 0, 1, afrB);            stageB(tb + 2, 0); BAR1(); MFMAS(0, 1, afrB); BAR2();
      LDB(1, 1); LDA(1, 1, 0, afrA); stageA(tb + 2, 0); BAR1(); MFMAS(1, 0, afrA); BAR2();
      LDA(1, 1, 1, afrB);            stageB(tb + 2, 1);
      waitcnt_vm<VM_LEAVE>();                           BAR1(); MFMAS(1, 1, afrB); BAR2();
    }
    {  // tail: tiles nt-2, nt-1; no further staging
      const int tb = nt - 1;
      LDB(0, 0); LDA(0, 0, 0, afrA); stageA(tb, 1); BAR1(); MFMAS(0, 0, afrA); BAR2();
      LDA(0, 0, 1, afrB);                           BAR1(); MFMAS(0, 1, afrB); BAR2();
      LDB(0, 1); LDA(0, 1, 0, afrA);                BAR1(); MFMAS(1, 0, afrA); BAR2();
      LDA(0, 1, 1, afrB); waitcnt_vm<0>();          BAR1(); MFMAS(1, 1, afrB); BAR2();
      LDB(1, 0); LDA(1, 0, 0, afrA);                BAR1(); MFMAS(0, 0, afrA); BAR2();
      LDA(1, 0, 1, afrB);                           BAR1(); MFMAS(0, 1, afrB); BAR2();
      LDB(1, 1); LDA(1, 1, 0, afrA);                BAR1(); MFMAS(1, 0, afrA); BAR2();
      LDA(1, 1, 1, afrB);                           BAR1(); MFMAS(1, 1, afrB); BAR2();
    }
#undef LDB
#undef LDA
#undef MFMAS
#undef BAR1
#undef BAR2

    // epilogue: D row = (lane>>4)*4 + j, col = lane&15 (m89-verified)
    const int cr0 = tm * BM + wr * (BM / WM) + (lane >> 4) * 4;
    const int cc0 = tn * BN + wc * (BN / WN) + (lane & 15);

    if (OUT == 3) {
      // E = exp(S/32) bf16, causal mask; shfl row-sum + one atomic per row
      // per wave-column.
      float* sums = (float*)aux + (long)z * 2048;
#pragma unroll
      for (int m = 0; m < MR; m++) {
        float rs[4] = {0.f, 0.f, 0.f, 0.f};
#pragma unroll
        for (int n = 0; n < NR; n++)
#pragma unroll
          for (int j = 0; j < 4; j++) {
            long row = cr0 + m * 16 + j;
            long col = cc0 + n * 16;
            float e = (col <= row) ? __expf(acc[m][n][j] * 0.03125f) : 0.f;
            ((bf16*)C)[row * (long)ldc + col] = __float2bfloat16(e);
            rs[j] += e;
          }
#pragma unroll
        for (int o = 1; o < 16; o <<= 1) {
#pragma unroll
          for (int j = 0; j < 4; j++) rs[j] += __shfl_xor(rs[j], o);
        }
        if ((lane & 15) == 0) {
#pragma unroll
          for (int j = 0; j < 4; j++)
            atomicAdd(&sums[cr0 + m * 16 + j], rs[j]);
        }
      }
    } else {
#pragma unroll
      for (int m = 0; m < MR; m++) {
        float inv[4];
        if (OUT == 4) {
          const float* sums = (const float*)aux + (long)z * 2048;
#pragma unroll
          for (int j = 0; j < 4; j++) inv[j] = 1.0f / sums[cr0 + m * 16 + j];
        }
#pragma unroll
        for (int n = 0; n < NR; n++)
#pragma unroll
          for (int j = 0; j < 4; j++) {
            long row = cr0 + m * 16 + j;
            long col = cc0 + n * 16;
            if (OUT == 1)
              ((bf16*)C)[row * (long)ldc + col] = __float2bfloat16(acc[m][n][j]);
            else if (OUT == 4)
              ((float*)C)[row * (long)ldc + col] = acc[m][n][j] * inv[j];
            else
              ((float*)C)[row * (long)ldc + col] = acc[m][n][j];
          }
      }
    }
  }
}

// ---------------------------------------------------------------------------
// fused fp32 -> bf16 convert for x, Wq, Wk, Wv + zero-fill of sums (32KB).
// blocks: [0,8192) x ; [8192,9216) Wq ; [9216,10240) Wk ; [10240,11264) Wv ;
//         [11264,11272) zero sums
// ---------------------------------------------------------------------------
__global__ __launch_bounds__(256) void cvt_all(const float* __restrict__ x,
                                               const float* __restrict__ wq,
                                               const float* __restrict__ wk,
                                               const float* __restrict__ wv,
                                               bf16* __restrict__ xb,
                                               bf16* __restrict__ wb,
                                               float* __restrict__ sums) {
  const int b = blockIdx.x;
  if (b >= 11264) {
    ((float4*)sums)[(b - 11264) * 256 + threadIdx.x] = float4{0.f, 0.f, 0.f, 0.f};
    return;
  }
  const float* src;
  bf16* dst;
  int i;
  if (b < 8192) { src = x; dst = xb; i = b * 256 + threadIdx.x; }
  else if (b < 9216) { src = wq; dst = wb; i = (b - 8192) * 256 + threadIdx.x; }
  else if (b < 10240) { src = wk; dst = wb + 1048576; i = (b - 9216) * 256 + threadIdx.x; }
  else { src = wv; dst = wb + 2097152; i = (b - 10240) * 256 + threadIdx.x; }
  float4 f = ((const float4*)src)[i];
  union { bf16 h[4]; uint2 u; } o;
  o.h[0] = __float2bfloat16(f.x);
  o.h[1] = __float2bfloat16(f.y);
  o.h[2] = __float2bfloat16(f.z);
  o.h[3] = __float2bfloat16(f.w);
  ((uint2*)dst)[i] = o.u;
}

// ---------------------------------------------------------------------------
// V (cols 2048.. of Cqkv, row stride 3072) -> Vt[b,d,s] (bf16), LDS 32x32
// ---------------------------------------------------------------------------
__global__ __launch_bounds__(256) void transposeV(const bf16* __restrict__ V,
                                                  bf16* __restrict__ Vt) {
  __shared__ bf16 t[32][33];
  const int b = blockIdx.z;
  const int s0 = blockIdx.x << 5;
  const int d0 = blockIdx.y << 5;
  const bf16* Vb = V + (long)b * 2048 * 3072;
  bf16* Vtb = Vt + (long)b * 1024 * 2048;
  const int lx = threadIdx.x & 31, ly = threadIdx.x >> 5;
#pragma unroll
  for (int r = 0; r < 32; r += 8)
    t[r + ly][lx] = Vb[(long)(s0 + r + ly) * 3072 + d0 + lx];
  __syncthreads();
#pragma unroll
  for (int r = 0; r < 32; r += 8)
    Vtb[(long)(d0 + r + ly) * 2048 + s0 + lx] = t[lx][r + ly];
}

// ---------------------------------------------------------------------------
// Workspace (160 MB):
//   [0,48M)    Cqkv bf16 [8192][3072]  (Q|K|V interleaved, ld=3072)
//   [48,64M)   Vt bf16 [4][1024][2048]
//   [64,96M)   E bf16 [4][2048][2048]  (exp(S/32), causal-masked)
//   [96M,+32K) sums fp32 [4][2048]     (atomic row-sums; zeroed by cvt_all)
//   [97,115M)  xb bf16 ; [115,121M) Wb bf16  (dead after QKV)
// ---------------------------------------------------------------------------
extern "C" void kernel_launch(void* const* d_in, const int* in_sizes, int n_in,
                              void* d_out, int out_size, void* d_ws, size_t ws_size,
                              hipStream_t stream) {
  const float* x = (const float*)d_in[0];
  const float* Wq = (const float*)d_in[1];
  const float* Wk = (const float*)d_in[2];
  const float* Wv = (const float*)d_in[3];

  const long MBy = 1 << 20;
  char* ws = (char*)d_ws;
  bf16* Cqkv = (bf16*)(ws);
  bf16* Vt = (bf16*)(ws + 48 * MBy);
  bf16* E = (bf16*)(ws + 64 * MBy);
  float* sums = (float*)(ws + 96 * MBy);
  bf16* xb = (bf16*)(ws + 97 * MBy);
  bf16* Wb = (bf16*)(ws + 115 * MBy);

  // 1) convert inputs to bf16 + zero sums (single dispatch)
  cvt_all<<<11272, 256, 0, stream>>>(x, Wq, Wk, Wv, xb, Wb, sums);

  // 2) fused QKV: [8192,3072] = xb * Wb^T. BM=256, BN=192, 8 waves (2x4,
  //    wave-tile 128x48), 112KB LDS, 512 blocks = 2 rounds. (61.8us, stable)
  gemmT<256, 192, 2, 4, 256, 2, 1, false, false, 1><<<dim3(16, 32), 512, 0, stream>>>(
      xb, Wb, Cqkv, 1024, 1024, 1024, 3072, 0L, 0L, 0L, nullptr);

  // 3) V transpose (V = Cqkv cols [2048,3072), row stride 3072)
  transposeV<<<dim3(64, 32, 4), 256, 0, stream>>>(Cqkv + 2048, Vt);

  // 4) scores+exp+rowsum: E = exp(Q*K^T/32) bf16 causal-masked; row-sums
  //    reduced in-epilogue and atomicAdd'ed into sums. 544 live blocks.
  gemmT<128, 128, 2, 2, 256, 2, 3, true, false, 1><<<dim3(16, 16, 4), 256, 0, stream>>>(
      Cqkv, Cqkv + 1024, E, 1024, 3072, 3072, 2048,
      2048L * 3072, 2048L * 3072, 2048L * 2048 * 2, sums);

  // 5) out = (E * Vt^T) / sums[row], fp32, causal K-limit, PAIRED row-tiles
  //    (y, 15-y): constant 2176 k-tile work per block (R13 proved unpaired
  //    scheduler-assigned co-residency loses to enforced balance).
  gemmT<128, 128, 2, 2, 256, 2, 4, false, true, 2><<<dim3(8, 8, 4), 256, 0, stream>>>(
      E, Vt, d_out, 2048, 2048, 2048, 1024,
      2048L * 2048, 1024L * 2048, 2048L * 1024 * 4, sums);
}